// Round 1
// baseline (1508.137 us; speedup 1.0000x reference)
//
#include <hip/hip_runtime.h>
#include <hip/hip_bf16.h>
#include <cmath>

// ---------------- Problem constants ----------------
#define BATCH    256
#define DMODEL   2048
#define DSSM     4096
#define DSTATE   128
#define DCONV    4
#define NHEADS   64
#define HEADDIM  64
#define CONVDIM  4352          // DSSM + 2*DSTATE
#define NPROJ    8448          // z (4096) + xBC (4352); dt (64) handled separately

typedef float  f32x4  __attribute__((ext_vector_type(4)));
typedef __bf16 bf16x8 __attribute__((ext_vector_type(8)));
typedef __bf16 bf16x4 __attribute__((ext_vector_type(4)));

// =====================================================================
// Generic NT GEMM:  C[M,N] = A[M,K] * B[N,K]^T   (fp32 in/out, bf16 MFMA)
// BK = 64, 256 threads = 4 waves, 16x16x32 bf16 MFMA.
// =====================================================================
template<int BM, int BN, int WROWS, int WCOLS>
__global__ __launch_bounds__(256) void gemm_bf16_nt(
    const float* __restrict__ A, const float* __restrict__ B,
    float* __restrict__ C, int K, int ldc)
{
    constexpr int BK = 64;
    constexpr int WM = BM / WROWS;
    constexpr int WN = BN / WCOLS;
    constexpr int MI = WM / 16;
    constexpr int NI = WN / 16;

    __shared__ __bf16 As[BM][BK + 8];   // +8 bf16 pad keeps 16B align, breaks bank stride
    __shared__ __bf16 Bs[BN][BK + 8];

    const int t    = threadIdx.x;
    const int n0   = blockIdx.x * BN;
    const int m0   = blockIdx.y * BM;
    const int lane = t & 63;
    const int wave = t >> 6;
    const int wr   = wave / WCOLS;
    const int wc   = wave % WCOLS;

    f32x4 acc[MI][NI] = {};

    const int r_a = t >> 4;          // 16 float4 per 64-wide K row
    const int c4  = (t & 15) * 4;

    for (int k0 = 0; k0 < K; k0 += BK) {
        // ---- stage A (BM x 64 fp32 -> bf16) ----
#pragma unroll
        for (int i = 0; i < BM / 16; ++i) {
            int r = r_a + i * 16;
            float4 v = *(const float4*)(A + (size_t)(m0 + r) * K + k0 + c4);
            bf16x4 h = { (__bf16)v.x, (__bf16)v.y, (__bf16)v.z, (__bf16)v.w };
            *(bf16x4*)(&As[r][c4]) = h;
        }
        // ---- stage B (BN x 64 fp32 -> bf16) ----
#pragma unroll
        for (int i = 0; i < BN / 16; ++i) {
            int r = r_a + i * 16;
            float4 v = *(const float4*)(B + (size_t)(n0 + r) * K + k0 + c4);
            bf16x4 h = { (__bf16)v.x, (__bf16)v.y, (__bf16)v.z, (__bf16)v.w };
            *(bf16x4*)(&Bs[r][c4]) = h;
        }
        __syncthreads();

        // ---- MFMA over the two K=32 halves ----
#pragma unroll
        for (int kk = 0; kk < 2; ++kk) {
            const int kb = kk * 32 + (lane >> 4) * 8;
            bf16x8 af[MI], bfv[NI];
#pragma unroll
            for (int mi = 0; mi < MI; ++mi)
                af[mi] = *(const bf16x8*)(&As[wr * WM + mi * 16 + (lane & 15)][kb]);
#pragma unroll
            for (int ni = 0; ni < NI; ++ni)
                bfv[ni] = *(const bf16x8*)(&Bs[wc * WN + ni * 16 + (lane & 15)][kb]);
#pragma unroll
            for (int mi = 0; mi < MI; ++mi)
#pragma unroll
                for (int ni = 0; ni < NI; ++ni)
                    acc[mi][ni] = __builtin_amdgcn_mfma_f32_16x16x32_bf16(
                        af[mi], bfv[ni], acc[mi][ni], 0, 0, 0);
        }
        __syncthreads();
    }

    // ---- epilogue: C/D layout col = lane&15, row = (lane>>4)*4 + reg ----
    const int row_l = (lane >> 4) * 4;
    const int col_l = lane & 15;
#pragma unroll
    for (int mi = 0; mi < MI; ++mi)
#pragma unroll
        for (int ni = 0; ni < NI; ++ni)
#pragma unroll
            for (int r = 0; r < 4; ++r) {
                int row = m0 + wr * WM + mi * 16 + row_l + r;
                int col = n0 + wc * WN + ni * 16 + col_l;
                C[(size_t)row * ldc + col] = acc[mi][ni][r];
            }
}

// =====================================================================
// dt in fp32 (exp-sensitive path): dt_raw = x @ Wdt^T, then softplus & dA
// One block per batch; wave handles 16 heads; 64-lane dot + shuffle reduce.
// =====================================================================
__global__ __launch_bounds__(256) void dt_kernel(
    const float* __restrict__ x, const float* __restrict__ Wdt,
    const float* __restrict__ dt_bias, const float* __restrict__ A_log,
    float* __restrict__ dt_sp, float* __restrict__ dA)
{
    __shared__ float xs[DMODEL];
    const int b = blockIdx.x;
    const float4* xr = (const float4*)(x + (size_t)b * DMODEL);
    for (int i = threadIdx.x; i < DMODEL / 4; i += 256)
        ((float4*)xs)[i] = xr[i];
    __syncthreads();

    const int lane = threadIdx.x & 63;
    const int wave = threadIdx.x >> 6;
    for (int hh = 0; hh < 16; ++hh) {
        const int h = wave * 16 + hh;
        const float4* wrow = (const float4*)(Wdt + (size_t)h * DMODEL);
        float acc = 0.f;
#pragma unroll
        for (int i = 0; i < 8; ++i) {
            float4 w  = wrow[lane + 64 * i];
            float4 xv = ((const float4*)xs)[lane + 64 * i];
            acc += w.x * xv.x + w.y * xv.y + w.z * xv.z + w.w * xv.w;
        }
        for (int off = 32; off; off >>= 1)
            acc += __shfl_down(acc, off, 64);
        if (lane == 0) {
            float v  = acc + dt_bias[h];
            float sp = (v > 20.f) ? v : log1pf(expf(v));
            float a  = -expf(A_log[h]);
            dt_sp[b * NHEADS + h] = sp;
            dA[b * NHEADS + h]    = expf(sp * a);
        }
    }
}

// =====================================================================
// Conv state shift + depthwise conv + silu
// =====================================================================
__global__ __launch_bounds__(256) void conv_kernel(
    const float* __restrict__ conv_in, const float* __restrict__ xbc_raw, // ld = NPROJ
    const float* __restrict__ conv_w, const float* __restrict__ conv_b,
    float* __restrict__ conv_out, float* __restrict__ xbc_act)
{
    const int i = blockIdx.x * 256 + threadIdx.x;     // 0 .. BATCH*CONVDIM
    const int b = i / CONVDIM;
    const int c = i - b * CONVDIM;

    float4 old = ((const float4*)conv_in)[i];
    float  xn  = xbc_raw[(size_t)b * NPROJ + c];
    float4 nw  = { old.y, old.z, old.w, xn };
    ((float4*)conv_out)[i] = nw;

    float4 w = ((const float4*)conv_w)[c];
    float  v = nw.x * w.x + nw.y * w.y + nw.z * w.z + nw.w * w.w + conv_b[c];
    float  s = v / (1.f + expf(-v));                  // silu
    xbc_act[i] = s;
}

// =====================================================================
// Fused SSM update: state = state*dA + dt*B⊗x ; y = state·C + D*x ; y*silu(z)
// One block per (b,h); thread = (p = tid>>2, n-chunk = tid&3 of 32)
// =====================================================================
__global__ __launch_bounds__(256) void ssm_kernel(
    const float* __restrict__ st_in, const float* __restrict__ xbc_act,
    const float* __restrict__ dt_sp, const float* __restrict__ dA,
    const float* __restrict__ zbuf, const float* __restrict__ Dvec,
    float* __restrict__ st_out, float* __restrict__ yfin)
{
    const int h = blockIdx.x;
    const int b = blockIdx.y;
    const int p = threadIdx.x >> 2;
    const int c = threadIdx.x & 3;

    const float dt = dt_sp[b * NHEADS + h];
    const float da = dA[b * NHEADS + h];
    const float* xb = xbc_act + (size_t)b * CONVDIM;
    const float xp  = xb[h * HEADDIM + p];
    const float dtx = dt * xp;

    const size_t so = ((((size_t)b * NHEADS + h) * HEADDIM) + p) * DSTATE + c * 32;
    const float4* si   = (const float4*)(st_in + so);
    float4*       sout = (float4*)(st_out + so);
    const float4* Bq = (const float4*)(xb + DSSM + c * 32);
    const float4* Cq = (const float4*)(xb + DSSM + DSTATE + c * 32);

    float ysum = 0.f;
#pragma unroll
    for (int i = 0; i < 8; ++i) {
        float4 s  = si[i];
        float4 Bv = Bq[i];
        float4 Cv = Cq[i];
        s.x = s.x * da + dtx * Bv.x;
        s.y = s.y * da + dtx * Bv.y;
        s.z = s.z * da + dtx * Bv.z;
        s.w = s.w * da + dtx * Bv.w;
        sout[i] = s;
        ysum += s.x * Cv.x + s.y * Cv.y + s.z * Cv.z + s.w * Cv.w;
    }
    ysum += __shfl_xor(ysum, 1, 64);
    ysum += __shfl_xor(ysum, 2, 64);
    if (c == 0) {
        float y  = ysum + Dvec[h] * xp;
        float zv = zbuf[(size_t)b * NPROJ + h * HEADDIM + p];
        float sz = zv / (1.f + expf(-zv));
        yfin[(size_t)b * DSSM + h * HEADDIM + p] = y * sz;
    }
}

// =====================================================================
extern "C" void kernel_launch(void* const* d_in, const int* in_sizes, int n_in,
                              void* d_out, int out_size, void* d_ws, size_t ws_size,
                              hipStream_t stream)
{
    const float* x       = (const float*)d_in[0];   // (256,1,2048)
    const float* conv_in = (const float*)d_in[1];   // (256,4352,4)
    const float* ssm_in  = (const float*)d_in[2];   // (256,64,64,128)
    const float* Win     = (const float*)d_in[3];   // (8512,2048)
    const float* convw   = (const float*)d_in[4];   // (4352,4)
    const float* convb   = (const float*)d_in[5];   // (4352,)
    const float* dtb     = (const float*)d_in[6];   // (64,)
    const float* alog    = (const float*)d_in[7];   // (64,)
    const float* Dv      = (const float*)d_in[8];   // (64,)
    const float* Wout    = (const float*)d_in[9];   // (2048,4096)

    float* out      = (float*)d_out;                       // 256*2048
    float* conv_out = out + (size_t)BATCH * DMODEL;        // 256*4352*4
    float* ssm_out  = conv_out + (size_t)BATCH * CONVDIM * DCONV;

    float* ws      = (float*)d_ws;
    float* zxbcdt  = ws;                                   // 256*8448
    float* xbc_act = ws + (size_t)BATCH * NPROJ;           // 256*4352
    float* dt_sp   = xbc_act + (size_t)BATCH * CONVDIM;    // 256*64
    float* dAb     = dt_sp + BATCH * NHEADS;               // 256*64
    float* yfin    = dAb + BATCH * NHEADS;                 // 256*4096

    // 1) z + xBC projection (bf16 MFMA): (256,8448) = x @ Win[0:8448]^T
    gemm_bf16_nt<64, 128, 1, 4><<<dim3(NPROJ / 128, BATCH / 64), 256, 0, stream>>>(
        x, Win, zxbcdt, DMODEL, NPROJ);

    // 2) dt in fp32 + softplus + dA
    dt_kernel<<<BATCH, 256, 0, stream>>>(
        x, Win + (size_t)NPROJ * DMODEL, dtb, alog, dt_sp, dAb);

    // 3) conv shift + depthwise conv + silu
    conv_kernel<<<(BATCH * CONVDIM) / 256, 256, 0, stream>>>(
        conv_in, zxbcdt + DSSM, convw, convb, conv_out, xbc_act);

    // 4) fused SSM state update + y + silu(z) gating
    ssm_kernel<<<dim3(NHEADS, BATCH), 256, 0, stream>>>(
        ssm_in, xbc_act, dt_sp, dAb, zxbcdt, Dv, ssm_out, yfin);

    // 5) out projection (bf16 MFMA): (256,2048) = yfin @ Wout^T
    gemm_bf16_nt<64, 64, 2, 2><<<dim3(DMODEL / 64, BATCH / 64), 256, 0, stream>>>(
        yfin, Wout, out, DSSM, DMODEL);
}